// Round 6
// baseline (4867.435 us; speedup 1.0000x reference)
//
#include <hip/hip_runtime.h>
#include <cstdint>
#include <cstddef>

typedef unsigned short u16;
typedef unsigned int   u32;
typedef __attribute__((ext_vector_type(8))) short bf16x8;   // 8 bf16 = 4 VGPRs
typedef __attribute__((ext_vector_type(4))) float f32x4;

typedef __attribute__((address_space(1))) const unsigned int as1c_uint;
typedef __attribute__((address_space(3))) unsigned int as3_uint;

__device__ __forceinline__ void async16(const void* g, void* l) {
  __builtin_amdgcn_global_load_lds((as1c_uint*)g, (as3_uint*)l, 16, 0, 0);
}
__device__ __forceinline__ float bf2f(u16 u) {
  return __uint_as_float(((u32)u) << 16);
}
__device__ __forceinline__ u16 f2bf(float x) {
  u32 u = __float_as_uint(x);
  u32 r = u + 0x7FFFu + ((u >> 16) & 1u);
  return (u16)(r >> 16);
}

// ---------------- fp32 -> bf16 convert (x) ----------------
__global__ void cvt_k(const float4* __restrict__ in, ushort4* __restrict__ out) {
  int i = blockIdx.x * 256 + threadIdx.x;
  float4 v = in[i];
  ushort4 o;
  o.x = f2bf(v.x); o.y = f2bf(v.y); o.z = f2bf(v.z); o.w = f2bf(v.w);
  out[i] = o;
}

// ---------------- transpose+convert: out[n*K+k] = bf16(in[k*N+n]) ----------------
__global__ void tr_k(const float* __restrict__ in, u16* __restrict__ out, int K, int N) {
  __shared__ u16 t[32][33];
  int bn = blockIdx.x * 32, bk = blockIdx.y * 32;
  int x = threadIdx.x, y = threadIdx.y;
#pragma unroll
  for (int i = 0; i < 32; i += 8)
    t[y + i][x] = f2bf(in[(size_t)(bk + y + i) * N + bn + x]);
  __syncthreads();
#pragma unroll
  for (int i = 0; i < 32; i += 8)
    out[(size_t)(bn + y + i) * K + bk + x] = t[x][y + i];
}

// ---------------- generic GEMM: C[M,N] = act(A[M,K] @ Bt[N,K]^T + bias) ----------------
__global__ __launch_bounds__(256) void gemm_k(
    const u16* __restrict__ A, const u16* __restrict__ Bt,
    const float* __restrict__ bias, u16* __restrict__ Cbf, float* __restrict__ Cf,
    int N, int K, int act) {
  __shared__ __align__(16) u16 As[128 * 32];
  __shared__ __align__(16) u16 Bs[128 * 32];
  int tid = threadIdx.x;
  int lane = tid & 63, w = tid >> 6;
  int wm = w >> 1, wn = w & 1;
  int mm = lane & 15, kh = lane >> 4;
  int m0 = blockIdx.y * 128, n0 = blockIdx.x * 128;

  f32x4 zero = {0.f, 0.f, 0.f, 0.f};
  f32x4 acc[4][4];
#pragma unroll
  for (int i = 0; i < 4; ++i)
#pragma unroll
    for (int j = 0; j < 4; ++j) acc[i][j] = zero;

  for (int kt = 0; kt < K; kt += 32) {
#pragma unroll
    for (int it = 0; it < 2; ++it) {
      int q = tid + it * 256;
      int row = q >> 2, kc = (q & 3) * 8;
      async16(A  + (size_t)(m0 + row) * K + kt + kc, &As[q * 8]);
      async16(Bt + (size_t)(n0 + row) * K + kt + kc, &Bs[q * 8]);
    }
    __syncthreads();
    bf16x8 av[4], bv[4];
#pragma unroll
    for (int i = 0; i < 4; ++i) {
      av[i] = *(const bf16x8*)&As[(wm * 64 + i * 16 + mm) * 32 + kh * 8];
      bv[i] = *(const bf16x8*)&Bs[(wn * 64 + i * 16 + mm) * 32 + kh * 8];
    }
#pragma unroll
    for (int im = 0; im < 4; ++im)
#pragma unroll
      for (int in = 0; in < 4; ++in)
        acc[im][in] = __builtin_amdgcn_mfma_f32_16x16x32_bf16(av[im], bv[in], acc[im][in], 0, 0, 0);
    __syncthreads();
  }

#pragma unroll
  for (int im = 0; im < 4; ++im)
#pragma unroll
    for (int in = 0; in < 4; ++in)
#pragma unroll
      for (int r = 0; r < 4; ++r) {
        int gm = m0 + wm * 64 + im * 16 + kh * 4 + r;
        int gn = n0 + wn * 64 + in * 16 + mm;
        float v = acc[im][in][r] + bias[gn];
        if (act) v = fmaxf(v, 0.f);
        size_t off = (size_t)gm * N + gn;
        if (Cbf) Cbf[off] = f2bf(v);
        if (Cf)  Cf[off]  = v;
      }
}

// ---------------- row L2-normalize [rows,256] bf16 -> bf16 (optional pack t<500) ------
__global__ __launch_bounds__(256) void norm_k(const u16* __restrict__ in,
                                              u16* __restrict__ out, int pack) {
  int row = blockIdx.x * 4 + (threadIdx.x >> 6);
  int lane = threadIdx.x & 63;
  ushort4 v = ((const ushort4*)(in + (size_t)row * 256))[lane];
  float a = bf2f(v.x), b = bf2f(v.y), c = bf2f(v.z), d = bf2f(v.w);
  float s = a * a + b * b + c * c + d * d;
#pragma unroll
  for (int o = 32; o; o >>= 1) s += __shfl_xor(s, o);
  float rn = rsqrtf(s);
  int orow = row;
  if (pack) {
    int bb = row >> 9, tt = row & 511;
    if (tt >= 500) return;
    orow = bb * 500 + tt;
  }
  ushort4 o4;
  o4.x = f2bf(a * rn); o4.y = f2bf(b * rn);
  o4.z = f2bf(c * rn); o4.w = f2bf(d * rn);
  *(ushort4*)(out + (size_t)orow * 256 + lane * 4) = o4;
}

// ---------------- persistent GRU: 16 WGs, each owns 32 h-cols, weights in VGPRs -------
// Step critical path: hbuf store (1KB) -> fence -> sync -> arrive -> poll -> h load.
// xi(t+1) prefetched EVERY step (incl. t=0) into double-buffered LDS; cf/cbf post-arrive.
#define HS 520  // LDS h row stride in u16: 1040 B = 16B aligned, 2-way bank alias (free)

__global__ __launch_bounds__(512, 1) void gru_k(
    const u16* __restrict__ xi, const float* __restrict__ WH,
    const float* __restrict__ BHN, float* __restrict__ cf,
    u16* __restrict__ cbf, u16* hbuf, u32* cnt) {
  __shared__ __align__(16) u16 hs[16 * HS];
  __shared__ float xis[2 * 1536];
  __shared__ float gts[1536];
  int tid = threadIdx.x;
  int lane = tid & 63, w = tid >> 6;       // 8 waves; waves 0..5 do MFMA
  int wg = blockIdx.x;                     // 0..15
  int c0 = wg * 32;
  int cb = tid >> 5, cl = tid & 31;        // combine-phase (b, col) mapping
  int mm = lane & 15, kh = lane >> 4;

  // persistent B-fragments: gate cols {r,u,n} x 16, k-major (fp32 weights -> bf16)
  bf16x8 wf[16];
  if (w < 6) {
    int gcol = (w >> 1) * 512 + c0 + (w & 1) * 16 + mm;
    int kb = kh * 8;
#pragma unroll
    for (int kk = 0; kk < 16; ++kk) {
      bf16x8 tf;
#pragma unroll
      for (int j = 0; j < 8; ++j)
        tf[j] = (short)f2bf(WH[(size_t)(kk * 32 + kb + j) * 1536 + gcol]);
      wf[kk] = tf;
    }
  }
  float bhn = BHN[c0 + cl];

  // xi lane->addr mapping: pos = tid + j*512 in [0,1536); LDS index == pos
  int xbb[3], xgc[3];
#pragma unroll
  for (int j = 0; j < 3; ++j) {
    int pos = tid + j * 512;
    int bb = pos / 96, q = pos - bb * 96;
    xbb[j] = bb;
    xgc[j] = (q >> 5) * 512 + c0 + (q & 31);
  }
  // pre-stage xi(t=0) into xis[0]
#pragma unroll
  for (int j = 0; j < 3; ++j)
    xis[tid + j * 512] = bf2f(xi[(size_t)xbb[j] * 512 * 1536 + xgc[j]]);

  for (int t = 0; t < 512; ++t) {
    // ---- phase A: prefetch xi(t+1) (EVERY step) + stage h_{t-1}, overlapped ----
    u16 p0 = 0, p1 = 0, p2 = 0;
    bool pf = (t < 511);
    if (pf) {   // issue first: loads overlap the h-load / LDS-zeroing below
      p0 = xi[((size_t)xbb[0] * 512 + t + 1) * 1536 + xgc[0]];
      p1 = xi[((size_t)xbb[1] * 512 + t + 1) * 1536 + xgc[1]];
      p2 = xi[((size_t)xbb[2] * 512 + t + 1) * 1536 + xgc[2]];
    }
    if (t == 0) {
      for (int i = tid; i < 16 * HS; i += 512) hs[i] = 0;
    } else {
      const u16* hb = hbuf + (size_t)(t & 1) * 8192;
      int colb = (tid & 31) * 16;
      const uint4* src = (const uint4*)(hb + cb * 512 + colb);
      uint4 v0 = src[0], v1 = src[1];     // h load: the critical-path RT
      *(uint4*)&hs[cb * HS + colb] = v0;
      *(uint4*)&hs[cb * HS + colb + 8] = v1;
    }
    if (pf) {
      float* xd = &xis[((t + 1) & 1) * 1536];
      xd[tid] = bf2f(p0); xd[tid + 512] = bf2f(p1); xd[tid + 1024] = bf2f(p2);
    }
    __syncthreads();

    // ---- phase B: hp = h @ WH[:, my 16 gate cols] ----
    if (w < 6) {
      f32x4 acc = {0.f, 0.f, 0.f, 0.f};
#pragma unroll
      for (int kk = 0; kk < 16; ++kk) {
        bf16x8 a = *(const bf16x8*)&hs[mm * HS + kk * 32 + kh * 8];
        acc = __builtin_amdgcn_mfma_f32_16x16x32_bf16(a, wf[kk], acc, 0, 0, 0);
      }
      int gc = (w >> 1) * 32 + (w & 1) * 16 + mm;
#pragma unroll
      for (int r = 0; r < 4; ++r) gts[(kh * 4 + r) * 96 + gc] = acc[r];
    }
    __syncthreads();

    // ---- phase C: combine; store ONLY hbuf before the fence ----
    const float* xc = &xis[(t & 1) * 1536];
    float xr = xc[cb * 96 + cl], xu = xc[cb * 96 + 32 + cl], xn = xc[cb * 96 + 64 + cl];
    float hr = gts[cb * 96 + cl], hu = gts[cb * 96 + 32 + cl], hn = gts[cb * 96 + 64 + cl];
    float hp = bf2f(hs[cb * HS + c0 + cl]);
    float r  = 1.f / (1.f + __expf(-(xr + hr)));
    float uu = 1.f / (1.f + __expf(-(xu + hu)));
    float nx = xn + r * (hn + bhn);
    float nn = 1.f - 2.f / (__expf(2.f * nx) + 1.f);   // tanh
    float hnew = (1.f - uu) * nn + uu * hp;
    u16 hb16 = f2bf(hnew);
    hbuf[(size_t)((t + 1) & 1) * 8192 + cb * 512 + c0 + cl] = hb16;

    __threadfence();   // drains only the 1KB hbuf slice (prior stores long done)
    __syncthreads();   // all threads' hbuf stores fenced before arrive
    if (tid == 0)
      __hip_atomic_fetch_add(&cnt[t], 1u, __ATOMIC_ACQ_REL, __HIP_MEMORY_SCOPE_AGENT);

    // ---- post-arrive: outputs (fire-and-forget, overlap the poll) ----
    size_t co = ((size_t)cb * 512 + t) * 512 + c0 + cl;
    cf[co]  = hnew;
    cbf[co] = hb16;

    if (tid == 0) {
      while (__hip_atomic_load(&cnt[t], __ATOMIC_ACQUIRE, __HIP_MEMORY_SCOPE_AGENT) < 16u)
        __builtin_amdgcn_s_sleep(2);
    }
    __syncthreads();
    __threadfence();   // acquire: invalidate caches before reading peers' hbuf
  }
}

// ---------------- S = p . zhat^T fused with exp/g-reduction + diag capture -----------
__global__ __launch_bounds__(256) void sgemm_k(
    const u16* __restrict__ P, const u16* __restrict__ Z,
    float* __restrict__ g, float* __restrict__ diag) {
  __shared__ __align__(16) u16 Ap[128 * 256];   // 64 KB: full-K A strip
  __shared__ __align__(16) u16 Bs[128 * 32];    // 8 KB
  __shared__ float gacc[128 * 128];             // 64 KB
  int tid = threadIdx.x;
  int lane = tid & 63, w = tid >> 6;
  int wm = w >> 1, wn = w & 1;
  int mm = lane & 15, kh = lane >> 4;
  int r0 = blockIdx.y * 128, t0 = blockIdx.x * 128;

#pragma unroll
  for (int it = 0; it < 16; ++it) {
    int q = tid + it * 256;
    int row = q >> 5, kc = (q & 31) * 8;
    async16(P + (size_t)(r0 + row) * 256 + kc, &Ap[q * 8]);
  }
  for (int i = tid; i < 128 * 128; i += 256) gacc[i] = 0.f;
  __syncthreads();

  f32x4 zero = {0.f, 0.f, 0.f, 0.f};
  for (int b = 0; b < 16; ++b) {
    int n0 = b * 512 + t0;
    f32x4 acc[4][4];
#pragma unroll
    for (int i = 0; i < 4; ++i)
#pragma unroll
      for (int j = 0; j < 4; ++j) acc[i][j] = zero;

    for (int kk = 0; kk < 8; ++kk) {
#pragma unroll
      for (int it = 0; it < 2; ++it) {
        int q = tid + it * 256;
        int row = q >> 2, kc = (q & 3) * 8;
        async16(Z + (size_t)(n0 + row) * 256 + kk * 32 + kc, &Bs[q * 8]);
      }
      __syncthreads();
      bf16x8 av[4], bv[4];
#pragma unroll
      for (int i = 0; i < 4; ++i) {
        av[i] = *(const bf16x8*)&Ap[(wm * 64 + i * 16 + mm) * 256 + kk * 32 + kh * 8];
        bv[i] = *(const bf16x8*)&Bs[(wn * 64 + i * 16 + mm) * 32 + kh * 8];
      }
#pragma unroll
      for (int im = 0; im < 4; ++im)
#pragma unroll
        for (int in = 0; in < 4; ++in)
          acc[im][in] = __builtin_amdgcn_mfma_f32_16x16x32_bf16(av[im], bv[in], acc[im][in], 0, 0, 0);
      __syncthreads();
    }
#pragma unroll
    for (int im = 0; im < 4; ++im)
#pragma unroll
      for (int in = 0; in < 4; ++in)
#pragma unroll
        for (int r = 0; r < 4; ++r) {
          int row = wm * 64 + im * 16 + kh * 4 + r;
          int col = wn * 64 + in * 16 + mm;
          float s10 = acc[im][in][r] * 10.f;          // S' = S / TEMP
          gacc[row * 128 + col] += __expf(s10 - 10.f);
          int ig = r0 + row;
          if (ig < 8000) {
            int bi = ig / 500;
            if (bi == b) {
              int ti = ig - bi * 500;
              int dt = t0 + col - ti;
              if (dt >= 1 && dt <= 12) diag[(size_t)ig * 12 + dt - 1] = s10;
            }
          }
        }
  }
  __syncthreads();
  for (int i = tid; i < 128 * 128; i += 256) {
    int row = i >> 7, col = i & 127;
    g[(size_t)(r0 + row) * 512 + t0 + col] = gacc[i];
  }
}

// ---------------- window logsumexp + loss partial sums (one wave per row) ------------
__global__ __launch_bounds__(256) void win_k(const float* __restrict__ g,
                                             const float* __restrict__ diag,
                                             float* __restrict__ acc) {
  __shared__ float lo[4][16], hi[4][16];
  int w = threadIdx.x >> 6, lane = threadIdx.x & 63;
  int row = blockIdx.x * 4 + w;
  const float* gr = g + (size_t)row * 512;
  float4 a = ((const float4*)gr)[lane * 2];
  float4 b = ((const float4*)gr)[lane * 2 + 1];
  float s = a.x + a.y + a.z + a.w + b.x + b.y + b.z + b.w;
#pragma unroll
  for (int o = 32; o; o >>= 1) s += __shfl_xor(s, o);
  if (lane == 0) { lo[w][0]=a.x; lo[w][1]=a.y; lo[w][2]=a.z; lo[w][3]=a.w;
                   lo[w][4]=b.x; lo[w][5]=b.y; lo[w][6]=b.z; lo[w][7]=b.w; }
  if (lane == 1) { lo[w][8]=a.x; lo[w][9]=a.y; lo[w][10]=a.z; lo[w][11]=a.w; }
  if (lane == 62){ hi[w][0]=b.x; hi[w][1]=b.y; hi[w][2]=b.z; hi[w][3]=b.w; }
  if (lane == 63){ hi[w][4]=a.x; hi[w][5]=a.y; hi[w][6]=a.z; hi[w][7]=a.w;
                   hi[w][8]=b.x; hi[w][9]=b.y; hi[w][10]=b.z; hi[w][11]=b.w; }
  __syncthreads();
  float term = 0.f;
  if (lane < 12) {
    int k = lane + 1;
    float pre = 0.f, suf = 0.f;
#pragma unroll
    for (int j = 0; j < 12; ++j) {
      if (j < k) pre += lo[w][j];     // g[0..k-1]
      if (j >= k) suf += hi[w][j];    // g[500+k .. 511]
    }
    float W = s - pre - suf;          // sum over t' in [k, k+500)
    term = diag[(size_t)row * 12 + lane] - __logf(W) - 10.f;
  }
#pragma unroll
  for (int o = 32; o; o >>= 1) term += __shfl_xor(term, o);
  if (lane == 0) atomicAdd(acc, term);
}

__global__ void fin_k(const float* acc, float* lout) {
  lout[0] = -acc[0] * (1.f / 96000.f);  // -(1/(12*8000)) * sum
}

// ============================== launch ==============================
extern "C" void kernel_launch(void* const* d_in, const int* in_sizes, int n_in,
                              void* d_out, int out_size, void* d_ws, size_t ws_size,
                              hipStream_t stream) {
  (void)in_sizes; (void)n_in; (void)out_size; (void)ws_size;
  const float* x    = (const float*)d_in[0];
  const float* ew1  = (const float*)d_in[1];
  const float* eb1  = (const float*)d_in[2];
  const float* ew2  = (const float*)d_in[3];
  const float* eb2  = (const float*)d_in[4];
  const float* ew3  = (const float*)d_in[5];
  const float* eb3  = (const float*)d_in[6];
  const float* gwi  = (const float*)d_in[7];
  const float* gbi  = (const float*)d_in[8];
  const float* gwh  = (const float*)d_in[9];
  const float* gbhn = (const float*)d_in[10];
  const float* pw1  = (const float*)d_in[11];
  const float* pb1  = (const float*)d_in[12];
  const float* pw2  = (const float*)d_in[13];
  const float* pb2  = (const float*)d_in[14];

  char* W = (char*)d_ws;
  u32*   cnt  = (u32*)W;
  float* lacc = (float*)(W + 2048);
  u16*   w1T  = (u16*)(W + 4096);
  u16*   w2T  = (u16*)(W + 135168);
  u16*   w3T  = (u16*)(W + 659456);
  u16*   wiT  = (u16*)(W + 921600);
  u16*   p1T  = (u16*)(W + 1708032);
  u16*   p2T  = (u16*)(W + 2232320);
  u16*   hbuf = (u16*)(W + 2494464);
  float* diag = (float*)(W + 2527232);
  u16*   zhat = (u16*)(W + 2911232);
  u16*   zbf  = (u16*)(W + 7105536);    // g3 out, dead after g4
  u16*   cbf  = (u16*)(W + 7105536);    // gru out (after zbf dead)
  u16*   ppk  = (u16*)(W + 7105536);    // norm2 out (after cbf dead)
  u16*   xi   = (u16*)(W + 15494144);
  u16*   xbf  = (u16*)(W + 15494144);   // alias (dead before xi written)
  u16*   h1   = (u16*)(W + 17591296);   // alias
  u16*   h2   = (u16*)(W + 25979904);   // alias
  float* g    = (float*)(W + 15494144); // alias (xi dead after gru)

  float* zf    = (float*)d_out;             // z  [16,512,256] fp32
  float* cf    = zf + 2097152;              // c  [16,512,512] fp32
  float* lout  = zf + 6291456;              // loss scalar fp32

  hipMemsetAsync(d_ws, 0, 4096, stream);    // zero barrier counters + loss acc

  cvt_k<<<1024, 256, 0, stream>>>((const float4*)x, (ushort4*)xbf);

  dim3 tb(32, 8);
  tr_k<<<dim3(16, 4),  tb, 0, stream>>>(ew1, w1T, 128, 512);
  tr_k<<<dim3(16, 16), tb, 0, stream>>>(ew2, w2T, 512, 512);
  tr_k<<<dim3(8, 16),  tb, 0, stream>>>(ew3, w3T, 512, 256);
  tr_k<<<dim3(48, 8),  tb, 0, stream>>>(gwi, wiT, 256, 1536);
  tr_k<<<dim3(16, 16), tb, 0, stream>>>(pw1, p1T, 512, 512);
  tr_k<<<dim3(8, 16),  tb, 0, stream>>>(pw2, p2T, 512, 256);

  gemm_k<<<dim3(4, 64),  256, 0, stream>>>(xbf,  w1T, eb1, h1,  nullptr, 512, 128, 1);
  gemm_k<<<dim3(4, 64),  256, 0, stream>>>(h1,   w2T, eb2, h2,  nullptr, 512, 512, 1);
  gemm_k<<<dim3(2, 64),  256, 0, stream>>>(h2,   w3T, eb3, zbf, zf,      256, 512, 0);
  norm_k<<<2048, 256, 0, stream>>>(zbf, zhat, 0);
  gemm_k<<<dim3(12, 64), 256, 0, stream>>>(zbf,  wiT, gbi, xi,  nullptr, 1536, 256, 0);
  gru_k<<<16, 512, 0, stream>>>(xi, gwh, gbhn, cf, cbf, hbuf, cnt);
  gemm_k<<<dim3(4, 64),  256, 0, stream>>>(cbf,  p1T, pb1, h1,  nullptr, 512, 512, 1);
  gemm_k<<<dim3(2, 64),  256, 0, stream>>>(h1,   p2T, pb2, h2,  nullptr, 256, 512, 0);
  norm_k<<<2048, 256, 0, stream>>>(h2, ppk, 1);
  sgemm_k<<<dim3(4, 63), 256, 0, stream>>>(ppk, zhat, g, diag);
  win_k<<<2000, 256, 0, stream>>>(g, diag, lacc);
  fin_k<<<1, 1, 0, stream>>>(lacc, lout);
}

// Round 7
// 2059.184 us; speedup vs baseline: 2.3638x; 2.3638x over previous
//
#include <hip/hip_runtime.h>
#include <cstdint>
#include <cstddef>

typedef unsigned short u16;
typedef unsigned int   u32;
typedef unsigned long long u64;
typedef __attribute__((ext_vector_type(8))) short bf16x8;   // 8 bf16 = 4 VGPRs
typedef __attribute__((ext_vector_type(4))) float f32x4;

typedef __attribute__((address_space(1))) const unsigned int as1c_uint;
typedef __attribute__((address_space(3))) unsigned int as3_uint;

__device__ __forceinline__ void async16(const void* g, void* l) {
  __builtin_amdgcn_global_load_lds((as1c_uint*)g, (as3_uint*)l, 16, 0, 0);
}
__device__ __forceinline__ float bf2f(u16 u) {
  return __uint_as_float(((u32)u) << 16);
}
__device__ __forceinline__ u16 f2bf(float x) {
  u32 u = __float_as_uint(x);
  u32 r = u + 0x7FFFu + ((u >> 16) & 1u);
  return (u16)(r >> 16);
}
// agent-scope relaxed atomics: sc0/sc1-flagged, bypass L1/L2, coherent at IC.
__device__ __forceinline__ void st32_ag(u32* p, u32 v) {
  __hip_atomic_store(p, v, __ATOMIC_RELAXED, __HIP_MEMORY_SCOPE_AGENT);
}
__device__ __forceinline__ u64 ld64_ag(const u64* p) {
  return __hip_atomic_load((u64*)p, __ATOMIC_RELAXED, __HIP_MEMORY_SCOPE_AGENT);
}

// ---------------- fp32 -> bf16 convert (x) ----------------
__global__ void cvt_k(const float4* __restrict__ in, ushort4* __restrict__ out) {
  int i = blockIdx.x * 256 + threadIdx.x;
  float4 v = in[i];
  ushort4 o;
  o.x = f2bf(v.x); o.y = f2bf(v.y); o.z = f2bf(v.z); o.w = f2bf(v.w);
  out[i] = o;
}

// ---------------- transpose+convert: out[n*K+k] = bf16(in[k*N+n]) ----------------
__global__ void tr_k(const float* __restrict__ in, u16* __restrict__ out, int K, int N) {
  __shared__ u16 t[32][33];
  int bn = blockIdx.x * 32, bk = blockIdx.y * 32;
  int x = threadIdx.x, y = threadIdx.y;
#pragma unroll
  for (int i = 0; i < 32; i += 8)
    t[y + i][x] = f2bf(in[(size_t)(bk + y + i) * N + bn + x]);
  __syncthreads();
#pragma unroll
  for (int i = 0; i < 32; i += 8)
    out[(size_t)(bn + y + i) * K + bk + x] = t[x][y + i];
}

// ---------------- generic GEMM: C[M,N] = act(A[M,K] @ Bt[N,K]^T + bias) ----------------
__global__ __launch_bounds__(256) void gemm_k(
    const u16* __restrict__ A, const u16* __restrict__ Bt,
    const float* __restrict__ bias, u16* __restrict__ Cbf, float* __restrict__ Cf,
    int N, int K, int act) {
  __shared__ __align__(16) u16 As[128 * 32];
  __shared__ __align__(16) u16 Bs[128 * 32];
  int tid = threadIdx.x;
  int lane = tid & 63, w = tid >> 6;
  int wm = w >> 1, wn = w & 1;
  int mm = lane & 15, kh = lane >> 4;
  int m0 = blockIdx.y * 128, n0 = blockIdx.x * 128;

  f32x4 zero = {0.f, 0.f, 0.f, 0.f};
  f32x4 acc[4][4];
#pragma unroll
  for (int i = 0; i < 4; ++i)
#pragma unroll
    for (int j = 0; j < 4; ++j) acc[i][j] = zero;

  for (int kt = 0; kt < K; kt += 32) {
#pragma unroll
    for (int it = 0; it < 2; ++it) {
      int q = tid + it * 256;
      int row = q >> 2, kc = (q & 3) * 8;
      async16(A  + (size_t)(m0 + row) * K + kt + kc, &As[q * 8]);
      async16(Bt + (size_t)(n0 + row) * K + kt + kc, &Bs[q * 8]);
    }
    __syncthreads();
    bf16x8 av[4], bv[4];
#pragma unroll
    for (int i = 0; i < 4; ++i) {
      av[i] = *(const bf16x8*)&As[(wm * 64 + i * 16 + mm) * 32 + kh * 8];
      bv[i] = *(const bf16x8*)&Bs[(wn * 64 + i * 16 + mm) * 32 + kh * 8];
    }
#pragma unroll
    for (int im = 0; im < 4; ++im)
#pragma unroll
      for (int in = 0; in < 4; ++in)
        acc[im][in] = __builtin_amdgcn_mfma_f32_16x16x32_bf16(av[im], bv[in], acc[im][in], 0, 0, 0);
    __syncthreads();
  }

#pragma unroll
  for (int im = 0; im < 4; ++im)
#pragma unroll
    for (int in = 0; in < 4; ++in)
#pragma unroll
      for (int r = 0; r < 4; ++r) {
        int gm = m0 + wm * 64 + im * 16 + kh * 4 + r;
        int gn = n0 + wn * 64 + in * 16 + mm;
        float v = acc[im][in][r] + bias[gn];
        if (act) v = fmaxf(v, 0.f);
        size_t off = (size_t)gm * N + gn;
        if (Cbf) Cbf[off] = f2bf(v);
        if (Cf)  Cf[off]  = v;
      }
}

// ---------------- row L2-normalize [rows,256] bf16 -> bf16 (optional pack t<500) ------
__global__ __launch_bounds__(256) void norm_k(const u16* __restrict__ in,
                                              u16* __restrict__ out, int pack) {
  int row = blockIdx.x * 4 + (threadIdx.x >> 6);
  int lane = threadIdx.x & 63;
  ushort4 v = ((const ushort4*)(in + (size_t)row * 256))[lane];
  float a = bf2f(v.x), b = bf2f(v.y), c = bf2f(v.z), d = bf2f(v.w);
  float s = a * a + b * b + c * c + d * d;
#pragma unroll
  for (int o = 32; o; o >>= 1) s += __shfl_xor(s, o);
  float rn = rsqrtf(s);
  int orow = row;
  if (pack) {
    int bb = row >> 9, tt = row & 511;
    if (tt >= 500) return;
    orow = bb * 500 + tt;
  }
  ushort4 o4;
  o4.x = f2bf(a * rn); o4.y = f2bf(b * rn);
  o4.z = f2bf(c * rn); o4.w = f2bf(d * rn);
  *(ushort4*)(out + (size_t)orow * 256 + lane * 4) = o4;
}

// ---------------- persistent GRU: 16 WGs, each owns 32 h-cols, weights in VGPRs -------
// h + barrier counter via agent-scope RELAXED atomics (sc0/sc1 -> Infinity Cache,
// XCD-coherent): NO threadfence / buffer_wbl2 / buffer_inv anywhere in the loop.
#define HS 520  // LDS h row stride in u16: 1040 B = 16B aligned, 2-way bank alias (free)

__global__ __launch_bounds__(512, 1) void gru_k(
    const u16* __restrict__ xi, const float* __restrict__ WH,
    const float* __restrict__ BHN, float* __restrict__ cf,
    u16* __restrict__ cbf, u16* hbuf, u32* cnt) {
  __shared__ __align__(16) u16 hs[16 * HS];
  __shared__ float xis[2 * 1536];
  __shared__ float gts[1536];
  int tid = threadIdx.x;
  int lane = tid & 63, w = tid >> 6;       // 8 waves; waves 0..5 do MFMA
  int wg = blockIdx.x;                     // 0..15
  int c0 = wg * 32;
  int cb = tid >> 5, cl = tid & 31;        // combine-phase (b, col) mapping
  int mm = lane & 15, kh = lane >> 4;

  // persistent B-fragments: gate cols {r,u,n} x 16, k-major (fp32 weights -> bf16)
  bf16x8 wf[16];
  if (w < 6) {
    int gcol = (w >> 1) * 512 + c0 + (w & 1) * 16 + mm;
    int kb = kh * 8;
#pragma unroll
    for (int kk = 0; kk < 16; ++kk) {
      bf16x8 tf;
#pragma unroll
      for (int j = 0; j < 8; ++j)
        tf[j] = (short)f2bf(WH[(size_t)(kk * 32 + kb + j) * 1536 + gcol]);
      wf[kk] = tf;
    }
  }
  float bhn = BHN[c0 + cl];

  // xi lane->addr mapping: pos = tid + j*512 in [0,1536); LDS index == pos
  int xbb[3], xgc[3];
#pragma unroll
  for (int j = 0; j < 3; ++j) {
    int pos = tid + j * 512;
    int bb = pos / 96, q = pos - bb * 96;
    xbb[j] = bb;
    xgc[j] = (q >> 5) * 512 + c0 + (q & 31);
  }
  // pre-stage xi(t=0) into xis[0]
#pragma unroll
  for (int j = 0; j < 3; ++j)
    xis[tid + j * 512] = bf2f(xi[(size_t)xbb[j] * 512 * 1536 + xgc[j]]);

  int colb = (tid & 31) * 16;              // h-staging: 16 u16 (32 B) per thread

  for (int t = 0; t < 512; ++t) {
    // ---- phase A: stage h_{t-1} (IC loads) + prefetch xi(t+1), overlapped ----
    if (t == 0) {
      for (int i = tid; i < 16 * HS; i += 512) hs[i] = 0;
    } else {
      const u64* hb64 = (const u64*)(hbuf + (size_t)(t & 1) * 8192 + cb * 512 + colb);
      u64 a0 = ld64_ag(hb64 + 0);
      u64 a1 = ld64_ag(hb64 + 1);
      u64 a2 = ld64_ag(hb64 + 2);
      u64 a3 = ld64_ag(hb64 + 3);
      u64* dst = (u64*)&hs[cb * HS + colb];
      dst[0] = a0; dst[1] = a1; dst[2] = a2; dst[3] = a3;
    }
    if (t < 511) {
      u16 p0 = xi[((size_t)xbb[0] * 512 + t + 1) * 1536 + xgc[0]];
      u16 p1 = xi[((size_t)xbb[1] * 512 + t + 1) * 1536 + xgc[1]];
      u16 p2 = xi[((size_t)xbb[2] * 512 + t + 1) * 1536 + xgc[2]];
      float* xd = &xis[((t + 1) & 1) * 1536];
      xd[tid] = bf2f(p0); xd[tid + 512] = bf2f(p1); xd[tid + 1024] = bf2f(p2);
    }
    __syncthreads();

    // ---- phase B: hp = h @ WH[:, my 16 gate cols] ----
    if (w < 6) {
      f32x4 acc = {0.f, 0.f, 0.f, 0.f};
#pragma unroll
      for (int kk = 0; kk < 16; ++kk) {
        bf16x8 a = *(const bf16x8*)&hs[mm * HS + kk * 32 + kh * 8];
        acc = __builtin_amdgcn_mfma_f32_16x16x32_bf16(a, wf[kk], acc, 0, 0, 0);
      }
      int gc = (w >> 1) * 32 + (w & 1) * 16 + mm;
#pragma unroll
      for (int r = 0; r < 4; ++r) gts[(kh * 4 + r) * 96 + gc] = acc[r];
    }
    __syncthreads();

    // ---- phase C: combine; publish h via IC store; arrive; outputs; poll ----
    const float* xc = &xis[(t & 1) * 1536];
    float xr = xc[cb * 96 + cl], xu = xc[cb * 96 + 32 + cl], xn = xc[cb * 96 + 64 + cl];
    float hr = gts[cb * 96 + cl], hu = gts[cb * 96 + 32 + cl], hn = gts[cb * 96 + 64 + cl];
    float hp = bf2f(hs[cb * HS + c0 + cl]);
    float r  = 1.f / (1.f + __expf(-(xr + hr)));
    float uu = 1.f / (1.f + __expf(-(xu + hu)));
    float nx = xn + r * (hn + bhn);
    float nn = 1.f - 2.f / (__expf(2.f * nx) + 1.f);   // tanh
    float hnew = (1.f - uu) * nn + uu * hp;
    u16 hb16 = f2bf(hnew);
    // pack with lane-neighbor (cl^1 is lane^1, same wave); even lane stores u32
    u32 nbv = (u32)(u16)__shfl_xor((int)hb16, 1);
    if ((cl & 1) == 0) {
      u32 packed = (u32)hb16 | (nbv << 16);
      st32_ag((u32*)(hbuf + (size_t)((t + 1) & 1) * 8192 + cb * 512 + c0 + cl), packed);
    }
    __asm__ volatile("s_waitcnt vmcnt(0)" ::: "memory");  // h stores at IC
    __syncthreads();
    if (tid == 0)
      __hip_atomic_fetch_add(&cnt[t], 1u, __ATOMIC_RELAXED, __HIP_MEMORY_SCOPE_AGENT);

    // outputs: plain cached stores, never fenced in-loop (kernel-end flush only)
    size_t co = ((size_t)cb * 512 + t) * 512 + c0 + cl;
    cf[co]  = hnew;
    cbf[co] = hb16;

    if (tid == 0) {
      while (__hip_atomic_load(&cnt[t], __ATOMIC_RELAXED, __HIP_MEMORY_SCOPE_AGENT) < 16u)
        __builtin_amdgcn_s_sleep(1);
    }
    __syncthreads();
  }
}

// ---------------- S = p . zhat^T fused with exp/g-reduction + diag capture -----------
__global__ __launch_bounds__(256) void sgemm_k(
    const u16* __restrict__ P, const u16* __restrict__ Z,
    float* __restrict__ g, float* __restrict__ diag) {
  __shared__ __align__(16) u16 Ap[128 * 256];   // 64 KB: full-K A strip
  __shared__ __align__(16) u16 Bs[128 * 32];    // 8 KB
  __shared__ float gacc[128 * 128];             // 64 KB
  int tid = threadIdx.x;
  int lane = tid & 63, w = tid >> 6;
  int wm = w >> 1, wn = w & 1;
  int mm = lane & 15, kh = lane >> 4;
  int r0 = blockIdx.y * 128, t0 = blockIdx.x * 128;

#pragma unroll
  for (int it = 0; it < 16; ++it) {
    int q = tid + it * 256;
    int row = q >> 5, kc = (q & 31) * 8;
    async16(P + (size_t)(r0 + row) * 256 + kc, &Ap[q * 8]);
  }
  for (int i = tid; i < 128 * 128; i += 256) gacc[i] = 0.f;
  __syncthreads();

  f32x4 zero = {0.f, 0.f, 0.f, 0.f};
  for (int b = 0; b < 16; ++b) {
    int n0 = b * 512 + t0;
    f32x4 acc[4][4];
#pragma unroll
    for (int i = 0; i < 4; ++i)
#pragma unroll
      for (int j = 0; j < 4; ++j) acc[i][j] = zero;

    for (int kk = 0; kk < 8; ++kk) {
#pragma unroll
      for (int it = 0; it < 2; ++it) {
        int q = tid + it * 256;
        int row = q >> 2, kc = (q & 3) * 8;
        async16(Z + (size_t)(n0 + row) * 256 + kk * 32 + kc, &Bs[q * 8]);
      }
      __syncthreads();
      bf16x8 av[4], bv[4];
#pragma unroll
      for (int i = 0; i < 4; ++i) {
        av[i] = *(const bf16x8*)&Ap[(wm * 64 + i * 16 + mm) * 256 + kk * 32 + kh * 8];
        bv[i] = *(const bf16x8*)&Bs[(wn * 64 + i * 16 + mm) * 32 + kh * 8];
      }
#pragma unroll
      for (int im = 0; im < 4; ++im)
#pragma unroll
        for (int in = 0; in < 4; ++in)
          acc[im][in] = __builtin_amdgcn_mfma_f32_16x16x32_bf16(av[im], bv[in], acc[im][in], 0, 0, 0);
      __syncthreads();
    }
#pragma unroll
    for (int im = 0; im < 4; ++im)
#pragma unroll
      for (int in = 0; in < 4; ++in)
#pragma unroll
        for (int r = 0; r < 4; ++r) {
          int row = wm * 64 + im * 16 + kh * 4 + r;
          int col = wn * 64 + in * 16 + mm;
          float s10 = acc[im][in][r] * 10.f;          // S' = S / TEMP
          gacc[row * 128 + col] += __expf(s10 - 10.f);
          int ig = r0 + row;
          if (ig < 8000) {
            int bi = ig / 500;
            if (bi == b) {
              int ti = ig - bi * 500;
              int dt = t0 + col - ti;
              if (dt >= 1 && dt <= 12) diag[(size_t)ig * 12 + dt - 1] = s10;
            }
          }
        }
  }
  __syncthreads();
  for (int i = tid; i < 128 * 128; i += 256) {
    int row = i >> 7, col = i & 127;
    g[(size_t)(r0 + row) * 512 + t0 + col] = gacc[i];
  }
}

// ---------------- window logsumexp + loss partial sums (one wave per row) ------------
__global__ __launch_bounds__(256) void win_k(const float* __restrict__ g,
                                             const float* __restrict__ diag,
                                             float* __restrict__ acc) {
  __shared__ float lo[4][16], hi[4][16];
  int w = threadIdx.x >> 6, lane = threadIdx.x & 63;
  int row = blockIdx.x * 4 + w;
  const float* gr = g + (size_t)row * 512;
  float4 a = ((const float4*)gr)[lane * 2];
  float4 b = ((const float4*)gr)[lane * 2 + 1];
  float s = a.x + a.y + a.z + a.w + b.x + b.y + b.z + b.w;
#pragma unroll
  for (int o = 32; o; o >>= 1) s += __shfl_xor(s, o);
  if (lane == 0) { lo[w][0]=a.x; lo[w][1]=a.y; lo[w][2]=a.z; lo[w][3]=a.w;
                   lo[w][4]=b.x; lo[w][5]=b.y; lo[w][6]=b.z; lo[w][7]=b.w; }
  if (lane == 1) { lo[w][8]=a.x; lo[w][9]=a.y; lo[w][10]=a.z; lo[w][11]=a.w; }
  if (lane == 62){ hi[w][0]=b.x; hi[w][1]=b.y; hi[w][2]=b.z; hi[w][3]=b.w; }
  if (lane == 63){ hi[w][4]=a.x; hi[w][5]=a.y; hi[w][6]=a.z; hi[w][7]=a.w;
                   hi[w][8]=b.x; hi[w][9]=b.y; hi[w][10]=b.z; hi[w][11]=b.w; }
  __syncthreads();
  float term = 0.f;
  if (lane < 12) {
    int k = lane + 1;
    float pre = 0.f, suf = 0.f;
#pragma unroll
    for (int j = 0; j < 12; ++j) {
      if (j < k) pre += lo[w][j];     // g[0..k-1]
      if (j >= k) suf += hi[w][j];    // g[500+k .. 511]
    }
    float W = s - pre - suf;          // sum over t' in [k, k+500)
    term = diag[(size_t)row * 12 + lane] - __logf(W) - 10.f;
  }
#pragma unroll
  for (int o = 32; o; o >>= 1) term += __shfl_xor(term, o);
  if (lane == 0) atomicAdd(acc, term);
}

__global__ void fin_k(const float* acc, float* lout) {
  lout[0] = -acc[0] * (1.f / 96000.f);  // -(1/(12*8000)) * sum
}

// ============================== launch ==============================
extern "C" void kernel_launch(void* const* d_in, const int* in_sizes, int n_in,
                              void* d_out, int out_size, void* d_ws, size_t ws_size,
                              hipStream_t stream) {
  (void)in_sizes; (void)n_in; (void)out_size; (void)ws_size;
  const float* x    = (const float*)d_in[0];
  const float* ew1  = (const float*)d_in[1];
  const float* eb1  = (const float*)d_in[2];
  const float* ew2  = (const float*)d_in[3];
  const float* eb2  = (const float*)d_in[4];
  const float* ew3  = (const float*)d_in[5];
  const float* eb3  = (const float*)d_in[6];
  const float* gwi  = (const float*)d_in[7];
  const float* gbi  = (const float*)d_in[8];
  const float* gwh  = (const float*)d_in[9];
  const float* gbhn = (const float*)d_in[10];
  const float* pw1  = (const float*)d_in[11];
  const float* pb1  = (const float*)d_in[12];
  const float* pw2  = (const float*)d_in[13];
  const float* pb2  = (const float*)d_in[14];

  char* W = (char*)d_ws;
  u32*   cnt  = (u32*)W;
  float* lacc = (float*)(W + 2048);
  u16*   w1T  = (u16*)(W + 4096);
  u16*   w2T  = (u16*)(W + 135168);
  u16*   w3T  = (u16*)(W + 659456);
  u16*   wiT  = (u16*)(W + 921600);
  u16*   p1T  = (u16*)(W + 1708032);
  u16*   p2T  = (u16*)(W + 2232320);
  u16*   hbuf = (u16*)(W + 2494464);
  float* diag = (float*)(W + 2527232);
  u16*   zhat = (u16*)(W + 2911232);
  u16*   zbf  = (u16*)(W + 7105536);    // g3 out, dead after g4
  u16*   cbf  = (u16*)(W + 7105536);    // gru out (after zbf dead)
  u16*   ppk  = (u16*)(W + 7105536);    // norm2 out (after cbf dead)
  u16*   xi   = (u16*)(W + 15494144);
  u16*   xbf  = (u16*)(W + 15494144);   // alias (dead before xi written)
  u16*   h1   = (u16*)(W + 17591296);   // alias
  u16*   h2   = (u16*)(W + 25979904);   // alias
  float* g    = (float*)(W + 15494144); // alias (xi dead after gru)

  float* zf    = (float*)d_out;             // z  [16,512,256] fp32
  float* cf    = zf + 2097152;              // c  [16,512,512] fp32
  float* lout  = zf + 6291456;              // loss scalar fp32

  hipMemsetAsync(d_ws, 0, 4096, stream);    // zero barrier counters + loss acc

  cvt_k<<<1024, 256, 0, stream>>>((const float4*)x, (ushort4*)xbf);

  dim3 tb(32, 8);
  tr_k<<<dim3(16, 4),  tb, 0, stream>>>(ew1, w1T, 128, 512);
  tr_k<<<dim3(16, 16), tb, 0, stream>>>(ew2, w2T, 512, 512);
  tr_k<<<dim3(8, 16),  tb, 0, stream>>>(ew3, w3T, 512, 256);
  tr_k<<<dim3(48, 8),  tb, 0, stream>>>(gwi, wiT, 256, 1536);
  tr_k<<<dim3(16, 16), tb, 0, stream>>>(pw1, p1T, 512, 512);
  tr_k<<<dim3(8, 16),  tb, 0, stream>>>(pw2, p2T, 512, 256);

  gemm_k<<<dim3(4, 64),  256, 0, stream>>>(xbf,  w1T, eb1, h1,  nullptr, 512, 128, 1);
  gemm_k<<<dim3(4, 64),  256, 0, stream>>>(h1,   w2T, eb2, h2,  nullptr, 512, 512, 1);
  gemm_k<<<dim3(2, 64),  256, 0, stream>>>(h2,   w3T, eb3, zbf, zf,      256, 512, 0);
  norm_k<<<2048, 256, 0, stream>>>(zbf, zhat, 0);
  gemm_k<<<dim3(12, 64), 256, 0, stream>>>(zbf,  wiT, gbi, xi,  nullptr, 1536, 256, 0);
  gru_k<<<16, 512, 0, stream>>>(xi, gwh, gbhn, cf, cbf, hbuf, cnt);
  gemm_k<<<dim3(4, 64),  256, 0, stream>>>(cbf,  p1T, pb1, h1,  nullptr, 512, 512, 1);
  gemm_k<<<dim3(2, 64),  256, 0, stream>>>(h1,   p2T, pb2, h2,  nullptr, 256, 512, 0);
  norm_k<<<2048, 256, 0, stream>>>(h2, ppk, 1);
  sgemm_k<<<dim3(4, 63), 256, 0, stream>>>(ppk, zhat, g, diag);
  win_k<<<2000, 256, 0, stream>>>(g, diag, lacc);
  fin_k<<<1, 1, 0, stream>>>(lacc, lout);
}

// Round 9
// 1903.498 us; speedup vs baseline: 2.5571x; 1.0818x over previous
//
#include <hip/hip_runtime.h>
#include <cstdint>
#include <cstddef>

typedef unsigned short u16;
typedef unsigned int   u32;
typedef unsigned long long u64;
typedef __attribute__((ext_vector_type(8))) short bf16x8;   // 8 bf16 = 4 VGPRs
typedef __attribute__((ext_vector_type(4))) float f32x4;
typedef __attribute__((ext_vector_type(4))) unsigned int u32x4;

typedef __attribute__((address_space(1))) const unsigned int as1c_uint;
typedef __attribute__((address_space(3))) unsigned int as3_uint;

__device__ __forceinline__ void async16(const void* g, void* l) {
  __builtin_amdgcn_global_load_lds((as1c_uint*)g, (as3_uint*)l, 16, 0, 0);
}
__device__ __forceinline__ float bf2f(u16 u) {
  return __uint_as_float(((u32)u) << 16);
}
__device__ __forceinline__ u16 f2bf(float x) {
  u32 u = __float_as_uint(x);
  u32 r = u + 0x7FFFu + ((u >> 16) & 1u);
  return (u16)(r >> 16);
}

// ---- IC-scope ops (sc0 sc1: bypass L1+L2, serviced at Infinity Cache — the
// cross-XCD coherence point; same transport R7 validated via relaxed-agent atomics) ----
__device__ __forceinline__ u32 ld_u32_ic(const void* p) {
  u32 v;
  asm volatile("global_load_dword %0, %1, off sc0 sc1\n\ts_waitcnt vmcnt(0)"
               : "=v"(v) : "v"(p) : "memory");
  return v;
}
__device__ __forceinline__ void st_u32_ic(void* p, u32 v) {
  asm volatile("global_store_dword %0, %1, off sc0 sc1" :: "v"(p), "v"(v) : "memory");
}
__device__ __forceinline__ void ld_h64_ic(const void* p, u32x4& a, u32x4& b,
                                          u32x4& c, u32x4& d) {
  asm volatile(
      "global_load_dwordx4 %0, %4, off sc0 sc1\n\t"
      "global_load_dwordx4 %1, %4, off offset:16 sc0 sc1\n\t"
      "global_load_dwordx4 %2, %4, off offset:32 sc0 sc1\n\t"
      "global_load_dwordx4 %3, %4, off offset:48 sc0 sc1\n\t"
      "s_waitcnt vmcnt(0)"
      : "=&v"(a), "=&v"(b), "=&v"(c), "=&v"(d) : "v"(p) : "memory");
}

// ---------------- fp32 -> bf16 convert (x) ----------------
__global__ void cvt_k(const float4* __restrict__ in, ushort4* __restrict__ out) {
  int i = blockIdx.x * 256 + threadIdx.x;
  float4 v = in[i];
  ushort4 o;
  o.x = f2bf(v.x); o.y = f2bf(v.y); o.z = f2bf(v.z); o.w = f2bf(v.w);
  out[i] = o;
}

// ---------------- transpose+convert: out[n*K+k] = bf16(in[k*N+n]) ----------------
__global__ void tr_k(const float* __restrict__ in, u16* __restrict__ out, int K, int N) {
  __shared__ u16 t[32][33];
  int bn = blockIdx.x * 32, bk = blockIdx.y * 32;
  int x = threadIdx.x, y = threadIdx.y;
#pragma unroll
  for (int i = 0; i < 32; i += 8)
    t[y + i][x] = f2bf(in[(size_t)(bk + y + i) * N + bn + x]);
  __syncthreads();
#pragma unroll
  for (int i = 0; i < 32; i += 8)
    out[(size_t)(bn + y + i) * K + bk + x] = t[x][y + i];
}

// ---------------- generic GEMM: C[M,N] = act(A[M,K] @ Bt[N,K]^T + bias) ----------------
__global__ __launch_bounds__(256) void gemm_k(
    const u16* __restrict__ A, const u16* __restrict__ Bt,
    const float* __restrict__ bias, u16* __restrict__ Cbf, float* __restrict__ Cf,
    int N, int K, int act) {
  __shared__ __align__(16) u16 As[128 * 32];
  __shared__ __align__(16) u16 Bs[128 * 32];
  int tid = threadIdx.x;
  int lane = tid & 63, w = tid >> 6;
  int wm = w >> 1, wn = w & 1;
  int mm = lane & 15, kh = lane >> 4;
  int m0 = blockIdx.y * 128, n0 = blockIdx.x * 128;

  f32x4 zero = {0.f, 0.f, 0.f, 0.f};
  f32x4 acc[4][4];
#pragma unroll
  for (int i = 0; i < 4; ++i)
#pragma unroll
    for (int j = 0; j < 4; ++j) acc[i][j] = zero;

  for (int kt = 0; kt < K; kt += 32) {
#pragma unroll
    for (int it = 0; it < 2; ++it) {
      int q = tid + it * 256;
      int row = q >> 2, kc = (q & 3) * 8;
      async16(A  + (size_t)(m0 + row) * K + kt + kc, &As[q * 8]);
      async16(Bt + (size_t)(n0 + row) * K + kt + kc, &Bs[q * 8]);
    }
    __syncthreads();
    bf16x8 av[4], bv[4];
#pragma unroll
    for (int i = 0; i < 4; ++i) {
      av[i] = *(const bf16x8*)&As[(wm * 64 + i * 16 + mm) * 32 + kh * 8];
      bv[i] = *(const bf16x8*)&Bs[(wn * 64 + i * 16 + mm) * 32 + kh * 8];
    }
#pragma unroll
    for (int im = 0; im < 4; ++im)
#pragma unroll
      for (int in = 0; in < 4; ++in)
        acc[im][in] = __builtin_amdgcn_mfma_f32_16x16x32_bf16(av[im], bv[in], acc[im][in], 0, 0, 0);
    __syncthreads();
  }

#pragma unroll
  for (int im = 0; im < 4; ++im)
#pragma unroll
    for (int in = 0; in < 4; ++in)
#pragma unroll
      for (int r = 0; r < 4; ++r) {
        int gm = m0 + wm * 64 + im * 16 + kh * 4 + r;
        int gn = n0 + wn * 64 + in * 16 + mm;
        float v = acc[im][in][r] + bias[gn];
        if (act) v = fmaxf(v, 0.f);
        size_t off = (size_t)gm * N + gn;
        if (Cbf) Cbf[off] = f2bf(v);
        if (Cf)  Cf[off]  = v;
      }
}

// ---------------- row L2-normalize [rows,256] bf16 -> bf16 (optional pack t<500) ------
__global__ __launch_bounds__(256) void norm_k(const u16* __restrict__ in,
                                              u16* __restrict__ out, int pack) {
  int row = blockIdx.x * 4 + (threadIdx.x >> 6);
  int lane = threadIdx.x & 63;
  ushort4 v = ((const ushort4*)(in + (size_t)row * 256))[lane];
  float a = bf2f(v.x), b = bf2f(v.y), c = bf2f(v.z), d = bf2f(v.w);
  float s = a * a + b * b + c * c + d * d;
#pragma unroll
  for (int o = 32; o; o >>= 1) s += __shfl_xor(s, o);
  float rn = rsqrtf(s);
  int orow = row;
  if (pack) {
    int bb = row >> 9, tt = row & 511;
    if (tt >= 500) return;
    orow = bb * 500 + tt;
  }
  ushort4 o4;
  o4.x = f2bf(a * rn); o4.y = f2bf(b * rn);
  o4.z = f2bf(c * rn); o4.w = f2bf(d * rn);
  *(ushort4*)(out + (size_t)orow * 256 + lane * 4) = o4;
}

// ---------------- persistent GRU: 16 WGs, exchange at Infinity Cache -----------------
// Flag-store barrier: publisher h-store(IC) -> vmcnt(0) -> flag-store(IC, fire&forget);
// readers poll their one flag then wide-load the h slice (IC). Waves 0-3: h exchange +
// combine; 0-5: MFMA; 6-7: xi prefetch (2-deep) + cf/cbf outputs (1-step delayed).
#define HS 520

__global__ __launch_bounds__(512, 1) void gru_k(
    const u16* __restrict__ xi, const float* __restrict__ WH,
    const float* __restrict__ BHN, float* __restrict__ cf,
    u16* __restrict__ cbf, u16* hbuf, u32* flags) {
  __shared__ __align__(16) u16 hs[16 * HS];
  __shared__ float xis[2 * 1536];
  __shared__ float gts[1536];
  __shared__ float hnf[512];

  int tid = threadIdx.x;
  int role = blockIdx.x;                   // 0..15
  int c0 = role * 32;

  int lane = tid & 63, w = tid >> 6;
  int mm = lane & 15, kh = lane >> 4;

  // persistent B-fragments (waves 0-5): gate cols {r,u,n} x 16, k-major
  bf16x8 wf[16];
  if (w < 6) {
    int gcol = (w >> 1) * 512 + c0 + (w & 1) * 16 + mm;
    int kb = kh * 8;
#pragma unroll
    for (int kk = 0; kk < 16; ++kk) {
      bf16x8 tf;
#pragma unroll
      for (int j = 0; j < 8; ++j)
        tf[j] = (short)f2bf(WH[(size_t)(kk * 32 + kb + j) * 1536 + gcol]);
      wf[kk] = tf;
    }
  }
  // combine constants (waves 0-3: 2 adjacent cols per thread)
  int cr = tid >> 4, cj = (tid & 15) * 2;
  float bhn0 = 0.f, bhn1 = 0.f;
  if (w < 4) { bhn0 = BHN[c0 + cj]; bhn1 = BHN[c0 + cj + 1]; }

  // xi pipeline (waves 6-7): 12 values/thread/step, 2-step prefetch
  int tt = tid - 384;
  size_t xoff[12];
  u16 xpre[12];
  if (w >= 6) {
#pragma unroll
    for (int j = 0; j < 12; ++j) {
      int v = j * 128 + tt;
      int b = v / 96, q = v - b * 96;
      int gcol = (q >> 5) * 512 + c0 + (q & 31);
      xoff[j] = (size_t)b * 512 * 1536 + gcol;
      xis[v] = bf2f(xi[xoff[j]]);                 // xi(t=0) -> slot 0
    }
#pragma unroll
    for (int j = 0; j < 12; ++j) xpre[j] = xi[xoff[j] + 1536];   // issue xi(1)
  }

  for (int t = 0; t < 512; ++t) {
    // ---- phase A ----
    if (w < 4) {                       // h staging via IC (clean vmcnt path)
      if (t == 0) {
        for (int i = tid; i < 16 * HS; i += 256) hs[i] = 0;
      } else {
        int iter = 0;
        const u32* fl = &flags[tid & 15];
        while (ld_u32_ic(fl) < (u32)t) { if (++iter > (1 << 22)) break; }
        const u16* hb = hbuf + (size_t)(t & 1) * 8192 + (tid >> 4) * 512 + (tid & 15) * 32;
        u32x4 a, b, c, d;
        ld_h64_ic(hb, a, b, c, d);
        u32x4* dst = (u32x4*)&hs[(tid >> 4) * HS + (tid & 15) * 32];
        dst[0] = a; dst[1] = b; dst[2] = c; dst[3] = d;
      }
    } else if (w >= 6) {               // outputs(t-1) + xi pipeline (own vmcnt)
      if (t > 0) {
        int v = tt * 4;
        int b = v >> 5, col = v & 31;
        size_t co = ((size_t)b * 512 + (t - 1)) * 512 + c0 + col;
        float4 o;
        o.x = hnf[v]; o.y = hnf[v + 1]; o.z = hnf[v + 2]; o.w = hnf[v + 3];
        *(float4*)&cf[co] = o;
        uint2 pk;
        pk.x = (u32)f2bf(o.x) | ((u32)f2bf(o.y) << 16);
        pk.y = (u32)f2bf(o.z) | ((u32)f2bf(o.w) << 16);
        *(uint2*)&cbf[co] = pk;
      }
      if (t < 511) {
        float* xd = &xis[((t + 1) & 1) * 1536];
#pragma unroll
        for (int j = 0; j < 12; ++j) xd[j * 128 + tt] = bf2f(xpre[j]);
      }
      if (t < 510) {
        const u16* xs = xi + (size_t)(t + 2) * 1536;
#pragma unroll
        for (int j = 0; j < 12; ++j) xpre[j] = xs[xoff[j]];
      }
    }
    __syncthreads();

    // ---- phase B: hp = h @ WH[:, my 16 gate cols] ----
    if (w < 6) {
      f32x4 acc = {0.f, 0.f, 0.f, 0.f};
#pragma unroll
      for (int kk = 0; kk < 16; ++kk) {
        bf16x8 a = *(const bf16x8*)&hs[mm * HS + kk * 32 + kh * 8];
        acc = __builtin_amdgcn_mfma_f32_16x16x32_bf16(a, wf[kk], acc, 0, 0, 0);
      }
      int gc = (w >> 1) * 32 + (w & 1) * 16 + mm;
#pragma unroll
      for (int r = 0; r < 4; ++r) gts[(kh * 4 + r) * 96 + gc] = acc[r];
    }
    __syncthreads();

    // ---- phase C: combine (waves 0-3, 2 cols/thread); publish h(IC); flag ----
    if (w < 4) {
      const float* xc = &xis[(t & 1) * 1536] + cr * 96;
      const float* gr_ = &gts[cr * 96];
      float hp0 = bf2f(hs[cr * HS + c0 + cj]);
      float hp1 = bf2f(hs[cr * HS + c0 + cj + 1]);
      float r0 = 1.f / (1.f + __expf(-(xc[cj] + gr_[cj])));
      float u0 = 1.f / (1.f + __expf(-(xc[32 + cj] + gr_[32 + cj])));
      float nx0 = xc[64 + cj] + r0 * (gr_[64 + cj] + bhn0);
      float n0 = 1.f - 2.f / (__expf(2.f * nx0) + 1.f);
      float h0 = (1.f - u0) * n0 + u0 * hp0;
      float r1 = 1.f / (1.f + __expf(-(xc[cj + 1] + gr_[cj + 1])));
      float u1 = 1.f / (1.f + __expf(-(xc[33 + cj] + gr_[33 + cj])));
      float nx1 = xc[65 + cj] + r1 * (gr_[65 + cj] + bhn1);
      float n1 = 1.f - 2.f / (__expf(2.f * nx1) + 1.f);
      float h1v = (1.f - u1) * n1 + u1 * hp1;
      hnf[cr * 32 + cj] = h0;
      hnf[cr * 32 + cj + 1] = h1v;
      u32 pk = (u32)f2bf(h0) | ((u32)f2bf(h1v) << 16);
      st_u32_ic(hbuf + (size_t)((t + 1) & 1) * 8192 + cr * 512 + c0 + cj, pk);
      asm volatile("s_waitcnt vmcnt(0)" ::: "memory");   // h at IC before flag
    }
    __syncthreads();
    if (tid == 0) st_u32_ic(&flags[role], (u32)(t + 1));
  }

  // epilogue: outputs for t=511
  if (w >= 6) {
    int v = tt * 4;
    int b = v >> 5, col = v & 31;
    size_t co = ((size_t)b * 512 + 511) * 512 + c0 + col;
    float4 o;
    o.x = hnf[v]; o.y = hnf[v + 1]; o.z = hnf[v + 2]; o.w = hnf[v + 3];
    *(float4*)&cf[co] = o;
    uint2 pk;
    pk.x = (u32)f2bf(o.x) | ((u32)f2bf(o.y) << 16);
    pk.y = (u32)f2bf(o.z) | ((u32)f2bf(o.w) << 16);
    *(uint2*)&cbf[co] = pk;
  }
}

// ---------------- S = p . zhat^T fused with exp/g-reduction + diag capture -----------
__global__ __launch_bounds__(256) void sgemm_k(
    const u16* __restrict__ P, const u16* __restrict__ Z,
    float* __restrict__ g, float* __restrict__ diag) {
  __shared__ __align__(16) u16 Ap[128 * 256];
  __shared__ __align__(16) u16 Bs[128 * 32];
  __shared__ float gacc[128 * 128];
  int tid = threadIdx.x;
  int lane = tid & 63, w = tid >> 6;
  int wm = w >> 1, wn = w & 1;
  int mm = lane & 15, kh = lane >> 4;
  int r0 = blockIdx.y * 128, t0 = blockIdx.x * 128;

#pragma unroll
  for (int it = 0; it < 16; ++it) {
    int q = tid + it * 256;
    int row = q >> 5, kc = (q & 31) * 8;
    async16(P + (size_t)(r0 + row) * 256 + kc, &Ap[q * 8]);
  }
  for (int i = tid; i < 128 * 128; i += 256) gacc[i] = 0.f;
  __syncthreads();

  f32x4 zero = {0.f, 0.f, 0.f, 0.f};
  for (int b = 0; b < 16; ++b) {
    int n0 = b * 512 + t0;
    f32x4 acc[4][4];
#pragma unroll
    for (int i = 0; i < 4; ++i)
#pragma unroll
      for (int j = 0; j < 4; ++j) acc[i][j] = zero;

    for (int kk = 0; kk < 8; ++kk) {
#pragma unroll
      for (int it = 0; it < 2; ++it) {
        int q = tid + it * 256;
        int row = q >> 2, kc = (q & 3) * 8;
        async16(Z + (size_t)(n0 + row) * 256 + kk * 32 + kc, &Bs[q * 8]);
      }
      __syncthreads();
      bf16x8 av[4], bv[4];
#pragma unroll
      for (int i = 0; i < 4; ++i) {
        av[i] = *(const bf16x8*)&Ap[(wm * 64 + i * 16 + mm) * 256 + kk * 32 + kh * 8];
        bv[i] = *(const bf16x8*)&Bs[(wn * 64 + i * 16 + mm) * 32 + kh * 8];
      }
#pragma unroll
      for (int im = 0; im < 4; ++im)
#pragma unroll
        for (int in = 0; in < 4; ++in)
          acc[im][in] = __builtin_amdgcn_mfma_f32_16x16x32_bf16(av[im], bv[in], acc[im][in], 0, 0, 0);
      __syncthreads();
    }
#pragma unroll
    for (int im = 0; im < 4; ++im)
#pragma unroll
      for (int in = 0; in < 4; ++in)
#pragma unroll
        for (int r = 0; r < 4; ++r) {
          int row = wm * 64 + im * 16 + kh * 4 + r;
          int col = wn * 64 + in * 16 + mm;
          float s10 = acc[im][in][r] * 10.f;
          gacc[row * 128 + col] += __expf(s10 - 10.f);
          int ig = r0 + row;
          if (ig < 8000) {
            int bi = ig / 500;
            if (bi == b) {
              int ti = ig - bi * 500;
              int dt = t0 + col - ti;
              if (dt >= 1 && dt <= 12) diag[(size_t)ig * 12 + dt - 1] = s10;
            }
          }
        }
  }
  __syncthreads();
  for (int i = tid; i < 128 * 128; i += 256) {
    int row = i >> 7, col = i & 127;
    g[(size_t)(r0 + row) * 512 + t0 + col] = gacc[i];
  }
}

// ---------------- window logsumexp + loss partial sums (one wave per row) ------------
__global__ __launch_bounds__(256) void win_k(const float* __restrict__ g,
                                             const float* __restrict__ diag,
                                             float* __restrict__ acc) {
  __shared__ float lo[4][16], hi[4][16];
  int w = threadIdx.x >> 6, lane = threadIdx.x & 63;
  int row = blockIdx.x * 4 + w;
  const float* gr = g + (size_t)row * 512;
  float4 a = ((const float4*)gr)[lane * 2];
  float4 b = ((const float4*)gr)[lane * 2 + 1];
  float s = a.x + a.y + a.z + a.w + b.x + b.y + b.z + b.w;
#pragma unroll
  for (int o = 32; o; o >>= 1) s += __shfl_xor(s, o);
  if (lane == 0) { lo[w][0]=a.x; lo[w][1]=a.y; lo[w][2]=a.z; lo[w][3]=a.w;
                   lo[w][4]=b.x; lo[w][5]=b.y; lo[w][6]=b.z; lo[w][7]=b.w; }
  if (lane == 1) { lo[w][8]=a.x; lo[w][9]=a.y; lo[w][10]=a.z; lo[w][11]=a.w; }
  if (lane == 62){ hi[w][0]=b.x; hi[w][1]=b.y; hi[w][2]=b.z; hi[w][3]=b.w; }
  if (lane == 63){ hi[w][4]=a.x; hi[w][5]=a.y; hi[w][6]=a.z; hi[w][7]=a.w;
                   hi[w][8]=b.x; hi[w][9]=b.y; hi[w][10]=b.z; hi[w][11]=b.w; }
  __syncthreads();
  float term = 0.f;
  if (lane < 12) {
    int k = lane + 1;
    float pre = 0.f, suf = 0.f;
#pragma unroll
    for (int j = 0; j < 12; ++j) {
      if (j < k) pre += lo[w][j];
      if (j >= k) suf += hi[w][j];
    }
    float W = s - pre - suf;
    term = diag[(size_t)row * 12 + lane] - __logf(W) - 10.f;
  }
#pragma unroll
  for (int o = 32; o; o >>= 1) term += __shfl_xor(term, o);
  if (lane == 0) atomicAdd(acc, term);
}

__global__ void fin_k(const float* acc, float* lout) {
  lout[0] = -acc[0] * (1.f / 96000.f);
}

// ============================== launch ==============================
extern "C" void kernel_launch(void* const* d_in, const int* in_sizes, int n_in,
                              void* d_out, int out_size, void* d_ws, size_t ws_size,
                              hipStream_t stream) {
  (void)in_sizes; (void)n_in; (void)out_size; (void)ws_size;
  const float* x    = (const float*)d_in[0];
  const float* ew1  = (const float*)d_in[1];
  const float* eb1  = (const float*)d_in[2];
  const float* ew2  = (const float*)d_in[3];
  const float* eb2  = (const float*)d_in[4];
  const float* ew3  = (const float*)d_in[5];
  const float* eb3  = (const float*)d_in[6];
  const float* gwi  = (const float*)d_in[7];
  const float* gbi  = (const float*)d_in[8];
  const float* gwh  = (const float*)d_in[9];
  const float* gbhn = (const float*)d_in[10];
  const float* pw1  = (const float*)d_in[11];
  const float* pb1  = (const float*)d_in[12];
  const float* pw2  = (const float*)d_in[13];
  const float* pb2  = (const float*)d_in[14];

  char* W = (char*)d_ws;
  u32*   flags = (u32*)(W + 64);        // [16] per-role step flags
  float* lacc = (float*)(W + 2048);
  u16*   w1T  = (u16*)(W + 4096);
  u16*   w2T  = (u16*)(W + 135168);
  u16*   w3T  = (u16*)(W + 659456);
  u16*   wiT  = (u16*)(W + 921600);
  u16*   p1T  = (u16*)(W + 1708032);
  u16*   p2T  = (u16*)(W + 2232320);
  u16*   hbuf = (u16*)(W + 2494464);
  float* diag = (float*)(W + 2527232);
  u16*   zhat = (u16*)(W + 2911232);
  u16*   zbf  = (u16*)(W + 7105536);    // g3 out, dead after g4
  u16*   cbf  = (u16*)(W + 7105536);    // gru out (after zbf dead)
  u16*   ppk  = (u16*)(W + 7105536);    // norm2 out (after cbf dead)
  u16*   xi   = (u16*)(W + 15494144);
  u16*   xbf  = (u16*)(W + 15494144);   // alias (dead before xi written)
  u16*   h1   = (u16*)(W + 17591296);   // alias
  u16*   h2   = (u16*)(W + 25979904);   // alias
  float* g    = (float*)(W + 15494144); // alias (xi dead after gru)

  float* zf    = (float*)d_out;
  float* cf    = zf + 2097152;
  float* lout  = zf + 6291456;

  hipMemsetAsync(d_ws, 0, 4096, stream);    // zero flags + lacc

  cvt_k<<<1024, 256, 0, stream>>>((const float4*)x, (ushort4*)xbf);

  dim3 tb(32, 8);
  tr_k<<<dim3(16, 4),  tb, 0, stream>>>(ew1, w1T, 128, 512);
  tr_k<<<dim3(16, 16), tb, 0, stream>>>(ew2, w2T, 512, 512);
  tr_k<<<dim3(8, 16),  tb, 0, stream>>>(ew3, w3T, 512, 256);
  tr_k<<<dim3(48, 8),  tb, 0, stream>>>(gwi, wiT, 256, 1536);
  tr_k<<<dim3(16, 16), tb, 0, stream>>>(pw1, p1T, 512, 512);
  tr_k<<<dim3(8, 16),  tb, 0, stream>>>(pw2, p2T, 512, 256);

  gemm_k<<<dim3(4, 64),  256, 0, stream>>>(xbf,  w1T, eb1, h1,  nullptr, 512, 128, 1);
  gemm_k<<<dim3(4, 64),  256, 0, stream>>>(h1,   w2T, eb2, h2,  nullptr, 512, 512, 1);
  gemm_k<<<dim3(2, 64),  256, 0, stream>>>(h2,   w3T, eb3, zbf, zf,      256, 512, 0);
  norm_k<<<2048, 256, 0, stream>>>(zbf, zhat, 0);
  gemm_k<<<dim3(12, 64), 256, 0, stream>>>(zbf,  wiT, gbi, xi,  nullptr, 1536, 256, 0);
  gru_k<<<16, 512, 0, stream>>>(xi, gwh, gbhn, cf, cbf, hbuf, flags);
  gemm_k<<<dim3(4, 64),  256, 0, stream>>>(cbf,  p1T, pb1, h1,  nullptr, 512, 512, 1);
  gemm_k<<<dim3(2, 64),  256, 0, stream>>>(h1,   p2T, pb2, h2,  nullptr, 256, 512, 0);
  norm_k<<<2048, 256, 0, stream>>>(h2, ppk, 1);
  sgemm_k<<<dim3(4, 63), 256, 0, stream>>>(ppk, zhat, g, diag);
  win_k<<<2000, 256, 0, stream>>>(g, diag, lacc);
  fin_k<<<1, 1, 0, stream>>>(lacc, lout);
}